// Round 1
// baseline (212.193 us; speedup 1.0000x reference)
//
#include <hip/hip_runtime.h>
#include <hip/hip_bf16.h>
#include <math.h>

// QLSTM: quantum gate collapses analytically to
//   qgate(x,p)[b,w] = prod_{j<=w} cos(p[j,1]) * cos(p[j,0] + x[b,j])
// Derivation: RX(p0)RX(x)=RX(p0+x); product state after 1q gates; CNOT chain
// maps Z_w -> Z_0..Z_w in Heisenberg picture; expectations factorize.

#define T_STEPS 128
#define B_SZ    256
#define D_IN    64
#define H_SZ    10
#define COMB    74   // D_IN + H_SZ

// ---------------- Kernel 1: Zx[t,b,g,w] = b_g[w] + x[t,b,:] . W_g[w,0:64] ----
__global__ __launch_bounds__(256) void qlstm_pre(
    const float* __restrict__ x,
    const float* __restrict__ Wf, const float* __restrict__ bf,
    const float* __restrict__ Wi, const float* __restrict__ bi,
    const float* __restrict__ Wu, const float* __restrict__ bu,
    const float* __restrict__ Wo, const float* __restrict__ bo,
    float* __restrict__ Zx)
{
    __shared__ float xs[64 * 64];       // 64 rows of x
    __shared__ float Wl[40 * 65];       // 40 (gate,w) rows, padded stride 65
    __shared__ float bl[40];

    const int tid = threadIdx.x;
    const long r0 = (long)blockIdx.x * 64;   // first (t*B+b) row of this block

    // stage 64 x-rows (4096 floats) coalesced as float4
    const float4* xin = (const float4*)(x + r0 * D_IN);
    float4* xs4 = (float4*)xs;
#pragma unroll
    for (int k = 0; k < 4; k++) xs4[tid + k * 256] = xin[tid + k * 256];

    const float* Ws[4] = {Wf, Wi, Wu, Wo};
    const float* bs[4] = {bf, bi, bu, bo};
    // stage W (first 64 cols of each 74-col row): 40*64 = 2560 floats
#pragma unroll
    for (int k = 0; k < 10; k++) {
        int i  = tid + k * 256;     // 0..2559
        int gw = i >> 6;            // 0..39
        int d  = i & 63;
        int g  = gw / 10, w = gw - g * 10;
        Wl[gw * 65 + d] = Ws[g][w * COMB + d];
    }
    if (tid < 40) { int g = tid / 10, w = tid - g * 10; bl[tid] = bs[g][w]; }
    __syncthreads();

#pragma unroll
    for (int k = 0; k < 10; k++) {
        int o  = k * 256 + tid;     // 0..2559  (= rl*40 + gw)
        int rl = o / 40;
        int gw = o - rl * 40;
        float acc = bl[gw];
        const float* xr = xs + rl * 64;
        const float* wr = Wl + gw * 65;
#pragma unroll
        for (int d = 0; d < 64; d++) acc = fmaf(xr[d], wr[d], acc);
        Zx[r0 * 40 + o] = acc;      // coalesced: (r0+rl)*40 + gw
    }
}

// ---------------- Kernel 2: sequential recurrence, one wave per batch -------
__global__ __launch_bounds__(64) void qlstm_rec(
    const float* __restrict__ Zx,
    const float* __restrict__ Wf, const float* __restrict__ Wi,
    const float* __restrict__ Wu, const float* __restrict__ Wo,
    const float* __restrict__ pf, const float* __restrict__ pi,
    const float* __restrict__ pu, const float* __restrict__ po,
    const float* __restrict__ ln_g, const float* __restrict__ ln_b,
    float* __restrict__ ys, float* __restrict__ outH, float* __restrict__ outC)
{
    const int b    = blockIdx.x;
    const int lane = threadIdx.x;
    const int g    = lane >> 4;        // gate 0..3 = f,i,u,o
    const int w    = lane & 15;        // wire 0..15 (10 active)
    const bool act = (w < H_SZ);

    const float* Ws[4] = {Wf, Wi, Wu, Wo};
    const float* ps[4] = {pf, pi, pu, po};

    // per-lane constants
    float wh[H_SZ];
#pragma unroll
    for (int j = 0; j < H_SZ; j++)
        wh[j] = act ? Ws[g][w * COMB + D_IN + j] : 0.f;
    const float p0  = act ? ps[g][w * 3 + 0] : 0.f;
    const float cp1 = act ? cosf(ps[g][w * 3 + 1]) : 1.f;
    const float lng = act ? ln_g[w] : 0.f;
    const float lnb = act ? ln_b[w] : 0.f;
    // activation: gate u (g==2) -> tanh(q); else sigmoid(q)=0.5+0.5*tanh(q/2)
    const float s0 = (g == 2) ? 0.f : 0.5f;
    const float s1 = (g == 2) ? 1.f : 0.5f;
    const float sc = (g == 2) ? 1.f : 0.5f;

    float hn = 0.f;   // lane's h[w] (post-LN), replicated across the 4 gate segments
    float cc = 0.f;   // lane's c[w]

    const float* zb = Zx + (size_t)b * 40 + g * 10 + w;
    float zcur = act ? zb[0] : 0.f;

    for (int t = 0; t < T_STEPS; t++) {
        // prefetch next step's pre-activation (hides L2 latency behind compute)
        float znext = (act && t < T_STEPS - 1) ? zb[(size_t)(t + 1) * B_SZ * 40] : 0.f;

        // z = Zx + Wh . h   (h gathered from lanes 0..9 via shuffle)
        float z = zcur;
#pragma unroll
        for (int j = 0; j < H_SZ; j++) z = fmaf(wh[j], __shfl(hn, j, 64), z);

        // per-wire <Z> factor, then segmented inclusive cumprod over w (width 16)
        float prod = act ? cp1 * cosf(p0 + z) : 1.f;
#pragma unroll
        for (int off = 1; off < 16; off <<= 1) {
            float v = __shfl_up(prod, off, 16);
            if (w >= off) prod *= v;
        }

        // branchless activation
        float av = fmaf(s1, tanhf(sc * prod), s0);

        // gather the 4 gates' activations for this lane's w
        float fw = __shfl(av, w,      64);
        float iw = __shfl(av, w + 16, 64);
        float uw = __shfl(av, w + 32, 64);
        float ow = __shfl(av, w + 48, 64);

        cc = fmaf(fw, cc, iw * uw);
        float hraw = fmaf(ow, tanhf(cc), hn);   // residual: + previous h

        // LayerNorm over the 10 wires (16-lane segment reduction, inactive=0)
        float v1 = act ? hraw : 0.f;
        float v2 = v1 * v1;
#pragma unroll
        for (int off = 1; off < 16; off <<= 1) {
            v1 += __shfl_xor(v1, off, 16);
            v2 += __shfl_xor(v2, off, 16);
        }
        float mu   = v1 * 0.1f;
        float varr = fmaxf(v2 * 0.1f - mu * mu, 0.f);
        float rstd = rsqrtf(varr + 1e-5f);
        float hnew = act ? fmaf((hraw - mu) * rstd, lng, lnb) : 0.f;

        if (lane < H_SZ)
            ys[(size_t)t * B_SZ * H_SZ + b * H_SZ + lane] = hnew;

        hn   = hnew;
        zcur = znext;
    }

    if (lane < H_SZ) {
        outH[b * H_SZ + lane] = hn;
        outC[b * H_SZ + lane] = cc;
    }
}

extern "C" void kernel_launch(void* const* d_in, const int* in_sizes, int n_in,
                              void* d_out, int out_size, void* d_ws, size_t ws_size,
                              hipStream_t stream)
{
    const float* x    = (const float*)d_in[0];
    const float* Wf   = (const float*)d_in[1];
    const float* bf   = (const float*)d_in[2];
    const float* pf   = (const float*)d_in[3];
    const float* Wi   = (const float*)d_in[4];
    const float* bi   = (const float*)d_in[5];
    const float* pi   = (const float*)d_in[6];
    const float* Wu   = (const float*)d_in[7];
    const float* bu   = (const float*)d_in[8];
    const float* pu   = (const float*)d_in[9];
    const float* Wo   = (const float*)d_in[10];
    const float* bo   = (const float*)d_in[11];
    const float* po   = (const float*)d_in[12];
    const float* ln_g = (const float*)d_in[13];
    const float* ln_b = (const float*)d_in[14];

    float* Zx = (float*)d_ws;                 // T*B*40 floats = 5.24 MB

    float* ys   = (float*)d_out;              // (T,B,H)
    float* outH = ys + (size_t)T_STEPS * B_SZ * H_SZ;
    float* outC = outH + (size_t)B_SZ * H_SZ;

    qlstm_pre<<<(T_STEPS * B_SZ) / 64, 256, 0, stream>>>(
        x, Wf, bf, Wi, bi, Wu, bu, Wo, bo, Zx);

    qlstm_rec<<<B_SZ, 64, 0, stream>>>(
        Zx, Wf, Wi, Wu, Wo, pf, pi, pu, po, ln_g, ln_b, ys, outH, outC);
}

// Round 2
// 157.893 us; speedup vs baseline: 1.3439x; 1.3439x over previous
//
#include <hip/hip_runtime.h>
#include <hip/hip_bf16.h>
#include <math.h>

// QLSTM: quantum gate collapses analytically to
//   qgate(x,p)[b,w] = prod_{j<=w} cos(p[j,1]) * cos(p[j,0] + x[b,j])
// (RX(p0)RX(x)=RX(p0+x); product state; CNOT chain -> Z_0..Z_w in Heisenberg
// picture; expectations factorize.)
//
// Round 2: latency-focused rec kernel (DPP cross-lane, native cos/exp/rcp/rsq,
// readlane h-dot, LayerNorm folded off the critical path) + register/uniform
// pre kernel (no LDS -> no ds_read_b32 storm).

#define T_STEPS 128
#define B_SZ    256
#define D_IN    64
#define H_SZ    10
#define COMB    74   // D_IN + H_SZ

// ---------------- DPP helpers (16-lane rows match our gate segments) --------
template<int CTRL>
__device__ __forceinline__ float dpp_mov(float old_, float src) {
    return __int_as_float(__builtin_amdgcn_update_dpp(
        __float_as_int(old_), __float_as_int(src), CTRL, 0xF, 0xF, false));
}
#define DPP_ROW_SHR(n) (0x110 + (n))
#define DPP_ROW_ROR(n) (0x120 + (n))

__device__ __forceinline__ float rdlane(float v, int lane) {
    return __int_as_float(__builtin_amdgcn_readlane(__float_as_int(v), lane));
}
__device__ __forceinline__ float bperm(int lane, float v) {
    return __int_as_float(__builtin_amdgcn_ds_bpermute(4 * lane, __float_as_int(v)));
}
__device__ __forceinline__ float frcp(float x) { return __builtin_amdgcn_rcpf(x); }

// ---------------- Kernel 1: Zx[row,gw] = b + x[row,:] . W[gw,0:64] ----------
// Thread = one row; x row in VGPRs; W addresses are wave-uniform -> scalar
// loads / L1-broadcast. No LDS at all.
__global__ __launch_bounds__(64) void qlstm_pre(
    const float* __restrict__ x,
    const float* __restrict__ Wf, const float* __restrict__ bf,
    const float* __restrict__ Wi, const float* __restrict__ bi,
    const float* __restrict__ Wu, const float* __restrict__ bu,
    const float* __restrict__ Wo, const float* __restrict__ bo,
    float* __restrict__ Zx)
{
    const long row = (long)blockIdx.x * 64 + threadIdx.x;   // 0..T*B-1

    float xr[64];
    const float4* xin = (const float4*)(x + row * D_IN);
#pragma unroll
    for (int k = 0; k < 16; k++) {
        float4 v = xin[k];
        xr[4*k+0] = v.x; xr[4*k+1] = v.y; xr[4*k+2] = v.z; xr[4*k+3] = v.w;
    }

    const float* Ws[4] = {Wf, Wi, Wu, Wo};
    const float* bs[4] = {bf, bi, bu, bo};
    float out[40];
#pragma unroll
    for (int g = 0; g < 4; g++) {
        const float* __restrict__ W  = Ws[g];
        const float* __restrict__ bb = bs[g];
#pragma unroll
        for (int w = 0; w < H_SZ; w++) {
            float acc = bb[w];                       // uniform
            const float* wr = W + w * COMB;          // uniform base
#pragma unroll
            for (int d = 0; d < 64; d++) acc = fmaf(xr[d], wr[d], acc);
            out[g * 10 + w] = acc;
        }
    }

    float4* zo = (float4*)(Zx + row * 40);           // 160B/row -> 16B aligned
#pragma unroll
    for (int k = 0; k < 10; k++)
        zo[k] = make_float4(out[4*k], out[4*k+1], out[4*k+2], out[4*k+3]);
}

// ---------------- Kernel 2: sequential recurrence, one wave per batch -------
__global__ __launch_bounds__(64) void qlstm_rec(
    const float* __restrict__ Zx,
    const float* __restrict__ Wf, const float* __restrict__ Wi,
    const float* __restrict__ Wu, const float* __restrict__ Wo,
    const float* __restrict__ pf, const float* __restrict__ pi,
    const float* __restrict__ pu, const float* __restrict__ po,
    const float* __restrict__ ln_g, const float* __restrict__ ln_b,
    float* __restrict__ ys, float* __restrict__ outH, float* __restrict__ outC)
{
    const int b    = blockIdx.x;
    const int lane = threadIdx.x;
    const int g    = lane >> 4;        // gate 0..3 = f,i,u,o
    const int w    = lane & 15;        // wire 0..15 (10 active)
    const bool act = (w < H_SZ);

    const float* Ws[4] = {Wf, Wi, Wu, Wo};
    const float* ps[4] = {pf, pi, pu, po};

    // per-lane constants; LN folded into the recurrence:
    //   sum_j wh[j]*hnew[j] = rstd*(sum_j wh'[j]*hraw[j] - mu*S) + A
    //   wh'[j]=wh[j]*ln_g[j], S=sum wh', A=sum wh[j]*ln_b[j]
    float whp[H_SZ];
    float S = 0.f, A = 0.f;
#pragma unroll
    for (int j = 0; j < H_SZ; j++) {
        float whj = act ? Ws[g][w * COMB + D_IN + j] : 0.f;
        whp[j] = whj * ln_g[j];
        S += whp[j];
        A  = fmaf(whj, ln_b[j], A);
    }
    const float p0  = act ? ps[g][w * 3 + 0] : 0.f;
    const float cp1 = act ? __cosf(ps[g][w * 3 + 1]) : 1.f;
    const float lng = act ? ln_g[w] : 0.f;
    const float lnb = act ? ln_b[w] : 0.f;
    // activation: gate u (g==2) tanh(q)=2/(1+e^-2q)-1; else sigmoid=1/(1+e^-q)
    const float a0   = (g == 2) ? -1.f : 0.f;
    const float a1   = (g == 2) ?  2.f : 1.f;
    const float aexp = (g == 2) ? -2.f : -1.f;

    float hn = 0.f;      // normalized h[w], replicated across 4 gate segments
    float cc = 0.f;      // c[w], replicated
    float hterm = 0.f;   // sum_j wh[j]*h[j] contribution to this lane's z

    const float* zb = Zx + (size_t)b * 40 + g * 10 + w;
    float zcur = act ? zb[0] : 0.f;

    for (int t = 0; t < T_STEPS; t++) {
        float znext = (act && t < T_STEPS - 1)
                    ? zb[(size_t)(t + 1) * B_SZ * 40] : 0.f;

        float z = zcur + hterm;

        // per-wire <Z> factor, segmented inclusive cumprod over w (DPP row ops)
        float prod = act ? cp1 * __cosf(p0 + z) : 1.f;
        prod *= dpp_mov<DPP_ROW_SHR(1)>(1.f, prod);
        prod *= dpp_mov<DPP_ROW_SHR(2)>(1.f, prod);
        prod *= dpp_mov<DPP_ROW_SHR(4)>(1.f, prod);
        prod *= dpp_mov<DPP_ROW_SHR(8)>(1.f, prod);

        // branchless fast activation
        float av = fmaf(a1, frcp(1.f + __expf(aexp * prod)), a0);

        // gather the 4 gates' activations for this lane's w
        float fw = bperm(w,      av);
        float iw = bperm(w + 16, av);
        float uw = bperm(w + 32, av);
        float ow = bperm(w + 48, av);

        cc = fmaf(fw, cc, iw * uw);
        float tc   = fmaf(2.f, frcp(1.f + __expf(-2.f * cc)), -1.f); // tanh(cc)
        float hraw = fmaf(ow, tc, hn);                               // residual

        // LN stats: rotate-allreduce over the 16-lane segment (inactive = 0)
        float v1 = act ? hraw : 0.f;
        float v2 = v1 * v1;
        v1 += dpp_mov<DPP_ROW_ROR(8)>(0.f, v1);
        v2 += dpp_mov<DPP_ROW_ROR(8)>(0.f, v2);
        v1 += dpp_mov<DPP_ROW_ROR(4)>(0.f, v1);
        v2 += dpp_mov<DPP_ROW_ROR(4)>(0.f, v2);
        v1 += dpp_mov<DPP_ROW_ROR(2)>(0.f, v1);
        v2 += dpp_mov<DPP_ROW_ROR(2)>(0.f, v2);
        v1 += dpp_mov<DPP_ROW_ROR(1)>(0.f, v1);
        v2 += dpp_mov<DPP_ROW_ROR(1)>(0.f, v2);

        // D = sum_j wh'[j]*hraw[j] via readlane (overlaps the reduction above)
        float d0 = whp[0] * rdlane(hraw, 0);
        float d1 = whp[1] * rdlane(hraw, 1);
        d0 = fmaf(whp[2], rdlane(hraw, 2), d0);
        d1 = fmaf(whp[3], rdlane(hraw, 3), d1);
        d0 = fmaf(whp[4], rdlane(hraw, 4), d0);
        d1 = fmaf(whp[5], rdlane(hraw, 5), d1);
        d0 = fmaf(whp[6], rdlane(hraw, 6), d0);
        d1 = fmaf(whp[7], rdlane(hraw, 7), d1);
        d0 = fmaf(whp[8], rdlane(hraw, 8), d0);
        d1 = fmaf(whp[9], rdlane(hraw, 9), d1);
        float D = d0 + d1;

        float mu   = v1 * 0.1f;
        float varr = fmaxf(fmaf(v2, 0.1f, -mu * mu), 0.f);
        float rstd = __builtin_amdgcn_rsqf(varr + 1e-5f);

        hn    = act ? fmaf((hraw - mu) * rstd, lng, lnb) : 0.f;
        hterm = fmaf(rstd, fmaf(-mu, S, D), A);

        if (lane < H_SZ)
            ys[(size_t)t * B_SZ * H_SZ + b * H_SZ + lane] = hn;

        zcur = znext;
    }

    if (lane < H_SZ) {
        outH[b * H_SZ + lane] = hn;
        outC[b * H_SZ + lane] = cc;
    }
}

extern "C" void kernel_launch(void* const* d_in, const int* in_sizes, int n_in,
                              void* d_out, int out_size, void* d_ws, size_t ws_size,
                              hipStream_t stream)
{
    const float* x    = (const float*)d_in[0];
    const float* Wf   = (const float*)d_in[1];
    const float* bf   = (const float*)d_in[2];
    const float* pf   = (const float*)d_in[3];
    const float* Wi   = (const float*)d_in[4];
    const float* bi   = (const float*)d_in[5];
    const float* pi   = (const float*)d_in[6];
    const float* Wu   = (const float*)d_in[7];
    const float* bu   = (const float*)d_in[8];
    const float* pu   = (const float*)d_in[9];
    const float* Wo   = (const float*)d_in[10];
    const float* bo   = (const float*)d_in[11];
    const float* po   = (const float*)d_in[12];
    const float* ln_g = (const float*)d_in[13];
    const float* ln_b = (const float*)d_in[14];

    float* Zx = (float*)d_ws;                 // T*B*40 floats = 5.24 MB

    float* ys   = (float*)d_out;              // (T,B,H)
    float* outH = ys + (size_t)T_STEPS * B_SZ * H_SZ;
    float* outC = outH + (size_t)B_SZ * H_SZ;

    qlstm_pre<<<(T_STEPS * B_SZ) / 64, 64, 0, stream>>>(
        x, Wf, bf, Wi, bi, Wu, bu, Wo, bo, Zx);

    qlstm_rec<<<B_SZ, 64, 0, stream>>>(
        Zx, Wf, Wi, Wu, Wo, pf, pi, pu, po, ln_g, ln_b, ys, outH, outC);
}

// Round 3
// 152.501 us; speedup vs baseline: 1.3914x; 1.0354x over previous
//
#include <hip/hip_runtime.h>
#include <hip/hip_bf16.h>
#include <math.h>

// QLSTM: quantum gate collapses analytically to
//   qgate(x,p)[b,w] = prod_{j<=w} cos(p[j,1]) * cos(p[j,0] + x[b,j])
// (RX(p0)RX(x)=RX(p0+x); product state; CNOT chain -> Z_0..Z_w in Heisenberg
// picture; expectations factorize.)
//
// Round 3: Zx transposed to [b][t][gw] so the rec wave streams its
// pre-activations sequentially (depth-3 register prefetch hides L2/L3
// latency); pre rewritten as LDS-W / register-x, issue-bound ~5us.

#define T_STEPS 128
#define B_SZ    256
#define D_IN    64
#define H_SZ    10
#define COMB    74   // D_IN + H_SZ

// ---------------- DPP helpers (16-lane rows match our gate segments) --------
template<int CTRL>
__device__ __forceinline__ float dpp_mov(float old_, float src) {
    return __int_as_float(__builtin_amdgcn_update_dpp(
        __float_as_int(old_), __float_as_int(src), CTRL, 0xF, 0xF, false));
}
#define DPP_ROW_SHR(n) (0x110 + (n))
#define DPP_ROW_ROR(n) (0x120 + (n))

__device__ __forceinline__ float rdlane(float v, int lane) {
    return __int_as_float(__builtin_amdgcn_readlane(__float_as_int(v), lane));
}
__device__ __forceinline__ float bperm(int lane, float v) {
    return __int_as_float(__builtin_amdgcn_ds_bpermute(4 * lane, __float_as_int(v)));
}
__device__ __forceinline__ float frcp(float x) { return __builtin_amdgcn_rcpf(x); }

// ---------------- Kernel 1: Zx[b][t][gw] = b + x[t,b,:] . W[gw,0:64] --------
// Thread = one (t,b) row. x row in VGPRs; W staged to LDS once per block and
// read back wave-uniform (broadcast) as b128.
__global__ __launch_bounds__(64) void qlstm_pre(
    const float* __restrict__ x,
    const float* __restrict__ Wf, const float* __restrict__ bf,
    const float* __restrict__ Wi, const float* __restrict__ bi,
    const float* __restrict__ Wu, const float* __restrict__ bu,
    const float* __restrict__ Wo, const float* __restrict__ bo,
    float* __restrict__ Zx)
{
    __shared__ float Wl[40 * 64];
    __shared__ float bl[40];

    const int tid = threadIdx.x;
    const long row = (long)blockIdx.x * 64 + tid;   // 0..T*B-1
    const int t = (int)(row >> 8);                  // row / 256
    const int b = (int)(row & 255);

    const float* Ws[4] = {Wf, Wi, Wu, Wo};
    const float* bs[4] = {bf, bi, bu, bo};
#pragma unroll
    for (int k = 0; k < 40; k++) {                  // coalesced 64-float rows
        int gg = k / 10, w = k - gg * 10;
        Wl[k * 64 + tid] = Ws[gg][w * COMB + tid];
    }
    if (tid < 40) { int gg = tid / 10, w = tid - gg * 10; bl[tid] = bs[gg][w]; }
    __syncthreads();

    float xr[64];
    const float4* xin = (const float4*)(x + row * D_IN);
#pragma unroll
    for (int k = 0; k < 16; k++) {
        float4 v = xin[k];
        xr[4*k+0] = v.x; xr[4*k+1] = v.y; xr[4*k+2] = v.z; xr[4*k+3] = v.w;
    }

    float4* zo = (float4*)(Zx + ((size_t)b * T_STEPS + t) * 40);
#pragma unroll
    for (int q = 0; q < 10; q++) {                  // 4 outputs per b128 store
        float o4[4];
#pragma unroll
        for (int j = 0; j < 4; j++) {
            const int gw = q * 4 + j;
            float acc = bl[gw];
            const float4* wr4 = (const float4*)(Wl + gw * 64);
#pragma unroll
            for (int d4 = 0; d4 < 16; d4++) {       // uniform ds_read_b128
                float4 wv = wr4[d4];
                acc = fmaf(xr[4*d4+0], wv.x, acc);
                acc = fmaf(xr[4*d4+1], wv.y, acc);
                acc = fmaf(xr[4*d4+2], wv.z, acc);
                acc = fmaf(xr[4*d4+3], wv.w, acc);
            }
            o4[j] = acc;
        }
        zo[q] = make_float4(o4[0], o4[1], o4[2], o4[3]);
    }
}

// ---------------- Kernel 2: sequential recurrence, one wave per batch -------
__global__ __launch_bounds__(64) void qlstm_rec(
    const float* __restrict__ Zx,
    const float* __restrict__ Wf, const float* __restrict__ Wi,
    const float* __restrict__ Wu, const float* __restrict__ Wo,
    const float* __restrict__ pf, const float* __restrict__ pi,
    const float* __restrict__ pu, const float* __restrict__ po,
    const float* __restrict__ ln_g, const float* __restrict__ ln_b,
    float* __restrict__ ys, float* __restrict__ outH, float* __restrict__ outC)
{
    const int b    = blockIdx.x;
    const int lane = threadIdx.x;
    const int g    = lane >> 4;        // gate 0..3 = f,i,u,o
    const int w    = lane & 15;        // wire 0..15 (10 active)
    const bool act = (w < H_SZ);

    const float* Ws[4] = {Wf, Wi, Wu, Wo};
    const float* ps[4] = {pf, pi, pu, po};

    // LN folded into the recurrence:
    //   sum_j wh[j]*hnew[j] = rstd*(sum_j wh'[j]*hraw[j] - mu*S) + A
    float whp[H_SZ];
    float S = 0.f, A = 0.f;
#pragma unroll
    for (int j = 0; j < H_SZ; j++) {
        float whj = act ? Ws[g][w * COMB + D_IN + j] : 0.f;
        whp[j] = whj * ln_g[j];
        S += whp[j];
        A  = fmaf(whj, ln_b[j], A);
    }
    const float p0  = act ? ps[g][w * 3 + 0] : 0.f;
    const float cp1 = act ? __cosf(ps[g][w * 3 + 1]) : 1.f;
    const float lng = act ? ln_g[w] : 0.f;
    const float lnb = act ? ln_b[w] : 0.f;
    const float a0   = (g == 2) ? -1.f : 0.f;   // tanh for gate u, sigmoid else
    const float a1   = (g == 2) ?  2.f : 1.f;
    const float aexp = (g == 2) ? -2.f : -1.f;

    float hn = 0.f;      // normalized h[w], replicated across 4 gate segments
    float cc = 0.f;      // c[w], replicated
    float hterm = 0.f;   // sum_j wh[j]*h[j] contribution to this lane's z

    // Zx[b][t][gw]: sequential 160B/step stream; depth-3 register prefetch
    const int gwl = g * 10 + (act ? w : 9);
    const float* zb = Zx + (size_t)b * (T_STEPS * 40) + gwl;
    float za = zb[0];
    float z1 = zb[40];
    float z2 = zb[80];

    for (int t = 0; t < T_STEPS; t++) {
        const int tp = (t + 3 < T_STEPS) ? t + 3 : T_STEPS - 1;
        float zn = zb[(size_t)tp * 40];

        float z = za + hterm;

        // per-wire <Z> factor, segmented inclusive cumprod over w (DPP)
        float prod = act ? cp1 * __cosf(p0 + z) : 1.f;
        prod *= dpp_mov<DPP_ROW_SHR(1)>(1.f, prod);
        prod *= dpp_mov<DPP_ROW_SHR(2)>(1.f, prod);
        prod *= dpp_mov<DPP_ROW_SHR(4)>(1.f, prod);
        prod *= dpp_mov<DPP_ROW_SHR(8)>(1.f, prod);

        // branchless fast activation
        float av = fmaf(a1, frcp(1.f + __expf(aexp * prod)), a0);

        // gather the 4 gates' activations for this lane's w
        float fw = bperm(w,      av);
        float iw = bperm(w + 16, av);
        float uw = bperm(w + 32, av);
        float ow = bperm(w + 48, av);

        cc = fmaf(fw, cc, iw * uw);
        float tc   = fmaf(2.f, frcp(1.f + __expf(-2.f * cc)), -1.f); // tanh
        float hraw = fmaf(ow, tc, hn);                               // residual

        // LN stats: rotate-allreduce over the 16-lane segment (inactive = 0)
        float v1 = act ? hraw : 0.f;
        float v2 = v1 * v1;
        v1 += dpp_mov<DPP_ROW_ROR(8)>(0.f, v1);
        v2 += dpp_mov<DPP_ROW_ROR(8)>(0.f, v2);
        v1 += dpp_mov<DPP_ROW_ROR(4)>(0.f, v1);
        v2 += dpp_mov<DPP_ROW_ROR(4)>(0.f, v2);
        v1 += dpp_mov<DPP_ROW_ROR(2)>(0.f, v1);
        v2 += dpp_mov<DPP_ROW_ROR(2)>(0.f, v2);
        v1 += dpp_mov<DPP_ROW_ROR(1)>(0.f, v1);
        v2 += dpp_mov<DPP_ROW_ROR(1)>(0.f, v2);

        // D = sum_j wh'[j]*hraw[j] via readlane (overlaps the DPP reduction)
        float d0 = whp[0] * rdlane(hraw, 0);
        float d1 = whp[1] * rdlane(hraw, 1);
        d0 = fmaf(whp[2], rdlane(hraw, 2), d0);
        d1 = fmaf(whp[3], rdlane(hraw, 3), d1);
        d0 = fmaf(whp[4], rdlane(hraw, 4), d0);
        d1 = fmaf(whp[5], rdlane(hraw, 5), d1);
        d0 = fmaf(whp[6], rdlane(hraw, 6), d0);
        d1 = fmaf(whp[7], rdlane(hraw, 7), d1);
        d0 = fmaf(whp[8], rdlane(hraw, 8), d0);
        d1 = fmaf(whp[9], rdlane(hraw, 9), d1);
        float D = d0 + d1;

        float mu   = v1 * 0.1f;
        float varr = fmaxf(fmaf(v2, 0.1f, -mu * mu), 0.f);
        float rstd = __builtin_amdgcn_rsqf(varr + 1e-5f);

        hn    = act ? fmaf((hraw - mu) * rstd, lng, lnb) : 0.f;
        hterm = fmaf(rstd, fmaf(-mu, S, D), A);

        if (lane < H_SZ)
            ys[(size_t)t * B_SZ * H_SZ + b * H_SZ + lane] = hn;

        za = z1; z1 = z2; z2 = zn;
    }

    if (lane < H_SZ) {
        outH[b * H_SZ + lane] = hn;
        outC[b * H_SZ + lane] = cc;
    }
}

extern "C" void kernel_launch(void* const* d_in, const int* in_sizes, int n_in,
                              void* d_out, int out_size, void* d_ws, size_t ws_size,
                              hipStream_t stream)
{
    const float* x    = (const float*)d_in[0];
    const float* Wf   = (const float*)d_in[1];
    const float* bf   = (const float*)d_in[2];
    const float* pf   = (const float*)d_in[3];
    const float* Wi   = (const float*)d_in[4];
    const float* bi   = (const float*)d_in[5];
    const float* pi   = (const float*)d_in[6];
    const float* Wu   = (const float*)d_in[7];
    const float* bu   = (const float*)d_in[8];
    const float* pu   = (const float*)d_in[9];
    const float* Wo   = (const float*)d_in[10];
    const float* bo   = (const float*)d_in[11];
    const float* po   = (const float*)d_in[12];
    const float* ln_g = (const float*)d_in[13];
    const float* ln_b = (const float*)d_in[14];

    float* Zx = (float*)d_ws;                 // B*T*40 floats = 5.24 MB

    float* ys   = (float*)d_out;              // (T,B,H)
    float* outH = ys + (size_t)T_STEPS * B_SZ * H_SZ;
    float* outC = outH + (size_t)B_SZ * H_SZ;

    qlstm_pre<<<(T_STEPS * B_SZ) / 64, 64, 0, stream>>>(
        x, Wf, bf, Wi, bi, Wu, bu, Wo, bo, Zx);

    qlstm_rec<<<B_SZ, 64, 0, stream>>>(
        Zx, Wf, Wi, Wu, Wo, pf, pi, pu, po, ln_g, ln_b, ys, outH, outC);
}

// Round 4
// 140.967 us; speedup vs baseline: 1.5053x; 1.0818x over previous
//
#include <hip/hip_runtime.h>
#include <hip/hip_bf16.h>
#include <math.h>

// QLSTM: quantum gate collapses analytically to
//   qgate(x,p)[b,w] = prod_{j<=w} cos(p[j,1]) * cos(p[j,0] + x[b,j])
// (RX(p0)RX(x)=RX(p0+x); product state; CNOT chain -> Z_0..Z_w in Heisenberg
// picture; expectations factorize.)
//
// Round 4: Zx layout [b][gw][t] -> each rec lane streams its z contiguously;
// dwordx4 loads cover 4 steps with a 2-buffer rotation = 8-step (~1800 cyc)
// real prefetch window, hiding HBM latency behind the serial-chain compute.
// Pre kernel: 2 rows/thread so each uniform ds_read_b128 of W feeds 8 FMAs.

#define T_STEPS 128
#define B_SZ    256
#define D_IN    64
#define H_SZ    10
#define COMB    74   // D_IN + H_SZ

// ---------------- DPP helpers (16-lane rows match our gate segments) --------
template<int CTRL>
__device__ __forceinline__ float dpp_mov(float old_, float src) {
    return __int_as_float(__builtin_amdgcn_update_dpp(
        __float_as_int(old_), __float_as_int(src), CTRL, 0xF, 0xF, false));
}
#define DPP_ROW_SHR(n) (0x110 + (n))
#define DPP_ROW_ROR(n) (0x120 + (n))

__device__ __forceinline__ float rdlane(float v, int lane) {
    return __int_as_float(__builtin_amdgcn_readlane(__float_as_int(v), lane));
}
__device__ __forceinline__ float bperm(int lane, float v) {
    return __int_as_float(__builtin_amdgcn_ds_bpermute(4 * lane, __float_as_int(v)));
}
__device__ __forceinline__ float frcp(float x) { return __builtin_amdgcn_rcpf(x); }

// ---------------- Kernel 1: Zx[b][gw][t] = b + x[t,b,:] . W[gw,0:64] --------
// 2 rows per thread: W staged once to LDS, read wave-uniform (broadcast b128),
// each read amortized over 8 FMAs. 64-thread blocks -> 1 wave/CU.
__global__ __launch_bounds__(64) void qlstm_pre(
    const float* __restrict__ x,
    const float* __restrict__ Wf, const float* __restrict__ bf,
    const float* __restrict__ Wi, const float* __restrict__ bi,
    const float* __restrict__ Wu, const float* __restrict__ bu,
    const float* __restrict__ Wo, const float* __restrict__ bo,
    float* __restrict__ Zx)
{
    __shared__ float Wl[40 * 64];
    __shared__ float bl[40];

    const int tid = threadIdx.x;
    const long r0 = (long)blockIdx.x * 128 + tid;   // rows r0 and r0+64
    const long r1 = r0 + 64;

    const float* Ws[4] = {Wf, Wi, Wu, Wo};
    const float* bs[4] = {bf, bi, bu, bo};
#pragma unroll
    for (int k = 0; k < 40; k++) {                  // coalesced 64-float rows
        int gg = k / 10, w = k - gg * 10;
        Wl[k * 64 + tid] = Ws[gg][w * COMB + tid];
    }
    if (tid < 40) { int gg = tid / 10, w = tid - gg * 10; bl[tid] = bs[gg][w]; }
    __syncthreads();

    float xr0[64], xr1[64];
    const float4* xin0 = (const float4*)(x + r0 * D_IN);
    const float4* xin1 = (const float4*)(x + r1 * D_IN);
#pragma unroll
    for (int k = 0; k < 16; k++) {
        float4 v0 = xin0[k];
        xr0[4*k+0] = v0.x; xr0[4*k+1] = v0.y; xr0[4*k+2] = v0.z; xr0[4*k+3] = v0.w;
        float4 v1 = xin1[k];
        xr1[4*k+0] = v1.x; xr1[4*k+1] = v1.y; xr1[4*k+2] = v1.z; xr1[4*k+3] = v1.w;
    }

    const int t0 = (int)(r0 >> 8), b0 = (int)(r0 & 255);
    const int t1 = (int)(r1 >> 8), b1 = (int)(r1 & 255);
    float* z0 = Zx + (size_t)b0 * 40 * T_STEPS + t0;
    float* z1 = Zx + (size_t)b1 * 40 * T_STEPS + t1;

#pragma unroll
    for (int gw = 0; gw < 40; gw++) {
        float a0 = bl[gw], a1 = bl[gw];
        const float4* wr4 = (const float4*)(Wl + gw * 64);
#pragma unroll
        for (int d4 = 0; d4 < 16; d4++) {           // uniform ds_read_b128
            float4 wv = wr4[d4];
            a0 = fmaf(xr0[4*d4+0], wv.x, a0);
            a0 = fmaf(xr0[4*d4+1], wv.y, a0);
            a0 = fmaf(xr0[4*d4+2], wv.z, a0);
            a0 = fmaf(xr0[4*d4+3], wv.w, a0);
            a1 = fmaf(xr1[4*d4+0], wv.x, a1);
            a1 = fmaf(xr1[4*d4+1], wv.y, a1);
            a1 = fmaf(xr1[4*d4+2], wv.z, a1);
            a1 = fmaf(xr1[4*d4+3], wv.w, a1);
        }
        z0[(size_t)gw * T_STEPS] = a0;              // [b][gw][t] scatter
        z1[(size_t)gw * T_STEPS] = a1;
    }
}

// ---------------- Kernel 2: sequential recurrence, one wave per batch -------
__global__ __launch_bounds__(64) void qlstm_rec(
    const float* __restrict__ Zx,
    const float* __restrict__ Wf, const float* __restrict__ Wi,
    const float* __restrict__ Wu, const float* __restrict__ Wo,
    const float* __restrict__ pf, const float* __restrict__ pi,
    const float* __restrict__ pu, const float* __restrict__ po,
    const float* __restrict__ ln_g, const float* __restrict__ ln_b,
    float* __restrict__ ys, float* __restrict__ outH, float* __restrict__ outC)
{
    const int b    = blockIdx.x;
    const int lane = threadIdx.x;
    const int g    = lane >> 4;        // gate 0..3 = f,i,u,o
    const int w    = lane & 15;        // wire 0..15 (10 active)
    const bool act = (w < H_SZ);

    const float* Ws[4] = {Wf, Wi, Wu, Wo};
    const float* ps[4] = {pf, pi, pu, po};

    // LN folded into the recurrence:
    //   sum_j wh[j]*hnew[j] = rstd*(sum_j wh'[j]*hraw[j] - mu*S) + A
    float whp[H_SZ];
    float S = 0.f, A = 0.f;
#pragma unroll
    for (int j = 0; j < H_SZ; j++) {
        float whj = act ? Ws[g][w * COMB + D_IN + j] : 0.f;
        whp[j] = whj * ln_g[j];
        S += whp[j];
        A  = fmaf(whj, ln_b[j], A);
    }
    const float p0  = act ? ps[g][w * 3 + 0] : 0.f;
    const float cp1 = act ? __cosf(ps[g][w * 3 + 1]) : 1.f;
    const float lng = act ? ln_g[w] : 0.f;
    const float lnb = act ? ln_b[w] : 0.f;
    const float s0   = (g == 2) ? -1.f : 0.f;   // tanh for gate u, sigmoid else
    const float s1   = (g == 2) ?  2.f : 1.f;
    const float sexp = (g == 2) ? -2.f : -1.f;

    float hn = 0.f;      // normalized h[w] (valid in lanes 0..9)
    float cc = 0.f;      // c[w]
    float hterm = 0.f;   // sum_j wh[j]*h[j] contribution to this lane's z

    // Zx[b][gw][t]: per-lane contiguous t-stream; 4 steps per dwordx4,
    // 2-buffer rotation -> loads consumed 8 steps after issue.
    const int gwl = g * 10 + (act ? w : 9);
    const float* zb = Zx + ((size_t)b * 40 + gwl) * T_STEPS;
    float4 zb0 = *(const float4*)(zb);
    float4 zb1 = *(const float4*)(zb + 4);

    float* ysb = ys + (size_t)b * H_SZ + lane;   // stride 2560 floats per t

    for (int gq = 0; gq < T_STEPS / 4; gq++) {
        float4 zc = zb0;
        zb0 = zb1;
        const int nl = (gq + 2 < T_STEPS / 4) ? gq + 2 : T_STEPS / 4 - 1;
        zb1 = *(const float4*)(zb + (size_t)nl * 4);

        float zs[4] = {zc.x, zc.y, zc.z, zc.w};
#pragma unroll
        for (int j = 0; j < 4; j++) {
            const int t = gq * 4 + j;
            float z = zs[j] + hterm;

            // per-wire <Z> factor, segmented inclusive cumprod (DPP row ops)
            float prod = cp1 * __cosf(p0 + z);
            prod *= dpp_mov<DPP_ROW_SHR(1)>(1.f, prod);
            prod *= dpp_mov<DPP_ROW_SHR(2)>(1.f, prod);
            prod *= dpp_mov<DPP_ROW_SHR(4)>(1.f, prod);
            prod *= dpp_mov<DPP_ROW_SHR(8)>(1.f, prod);

            // branchless fast activation (sigmoid / tanh via exp+rcp)
            float av = fmaf(s1, frcp(1.f + __expf(sexp * prod)), s0);

            // gather the 4 gates' activations for this lane's w
            float fw = bperm(w,      av);
            float iw = bperm(w + 16, av);
            float uw = bperm(w + 32, av);
            float ow = bperm(w + 48, av);

            cc = fmaf(fw, cc, iw * uw);
            float tc   = fmaf(2.f, frcp(1.f + __expf(-2.f * cc)), -1.f);
            float hraw = fmaf(ow, tc, hn);                 // residual skip

            // LN stats: rotate-allreduce over the 16-lane segment
            float v1 = act ? hraw : 0.f;
            float v2 = v1 * v1;
            v1 += dpp_mov<DPP_ROW_ROR(8)>(0.f, v1);
            v2 += dpp_mov<DPP_ROW_ROR(8)>(0.f, v2);
            v1 += dpp_mov<DPP_ROW_ROR(4)>(0.f, v1);
            v2 += dpp_mov<DPP_ROW_ROR(4)>(0.f, v2);
            v1 += dpp_mov<DPP_ROW_ROR(2)>(0.f, v1);
            v2 += dpp_mov<DPP_ROW_ROR(2)>(0.f, v2);
            v1 += dpp_mov<DPP_ROW_ROR(1)>(0.f, v1);
            v2 += dpp_mov<DPP_ROW_ROR(1)>(0.f, v2);

            // D = sum_j wh'[j]*hraw[j] via readlane (overlaps the DPP reduce)
            float d0 = whp[0] * rdlane(hraw, 0);
            float d1 = whp[1] * rdlane(hraw, 1);
            d0 = fmaf(whp[2], rdlane(hraw, 2), d0);
            d1 = fmaf(whp[3], rdlane(hraw, 3), d1);
            d0 = fmaf(whp[4], rdlane(hraw, 4), d0);
            d1 = fmaf(whp[5], rdlane(hraw, 5), d1);
            d0 = fmaf(whp[6], rdlane(hraw, 6), d0);
            d1 = fmaf(whp[7], rdlane(hraw, 7), d1);
            d0 = fmaf(whp[8], rdlane(hraw, 8), d0);
            d1 = fmaf(whp[9], rdlane(hraw, 9), d1);
            float D = d0 + d1;

            float mu   = v1 * 0.1f;
            float varr = fmaxf(fmaf(v2, 0.1f, -mu * mu), 0.f);
            float rstd = __builtin_amdgcn_rsqf(varr + 1e-5f);

            hn    = fmaf((hraw - mu) * rstd, lng, lnb);
            hterm = fmaf(rstd, fmaf(-mu, S, D), A);

            if (lane < H_SZ)
                ysb[(size_t)t * B_SZ * H_SZ] = hn;
        }
    }

    if (lane < H_SZ) {
        outH[b * H_SZ + lane] = hn;
        outC[b * H_SZ + lane] = cc;
    }
}

extern "C" void kernel_launch(void* const* d_in, const int* in_sizes, int n_in,
                              void* d_out, int out_size, void* d_ws, size_t ws_size,
                              hipStream_t stream)
{
    const float* x    = (const float*)d_in[0];
    const float* Wf   = (const float*)d_in[1];
    const float* bf   = (const float*)d_in[2];
    const float* pf   = (const float*)d_in[3];
    const float* Wi   = (const float*)d_in[4];
    const float* bi   = (const float*)d_in[5];
    const float* pi   = (const float*)d_in[6];
    const float* Wu   = (const float*)d_in[7];
    const float* bu   = (const float*)d_in[8];
    const float* pu   = (const float*)d_in[9];
    const float* Wo   = (const float*)d_in[10];
    const float* bo   = (const float*)d_in[11];
    const float* po   = (const float*)d_in[12];
    const float* ln_g = (const float*)d_in[13];
    const float* ln_b = (const float*)d_in[14];

    float* Zx = (float*)d_ws;                 // B*40*T floats = 5.24 MB

    float* ys   = (float*)d_out;              // (T,B,H)
    float* outH = ys + (size_t)T_STEPS * B_SZ * H_SZ;
    float* outC = outH + (size_t)B_SZ * H_SZ;

    qlstm_pre<<<(T_STEPS * B_SZ) / 128, 64, 0, stream>>>(
        x, Wf, bf, Wi, bi, Wu, bu, Wo, bo, Zx);

    qlstm_rec<<<B_SZ, 64, 0, stream>>>(
        Zx, Wf, Wi, Wu, Wo, pf, pi, pu, po, ln_g, ln_b, ys, outH, outC);
}

// Round 5
// 140.858 us; speedup vs baseline: 1.5064x; 1.0008x over previous
//
#include <hip/hip_runtime.h>
#include <hip/hip_bf16.h>
#include <math.h>

// QLSTM: quantum gate collapses analytically to
//   qgate(x,p)[b,w] = prod_{j<=w} cos(p[j,1]) * cos(p[j,0] + x[b,j])
// (RX(p0)RX(x)=RX(p0+x); product state; CNOT chain -> Z_0..Z_w in Heisenberg
// picture; expectations factorize.)
//
// Round 5: kill the 6-deep transcendental chain. |prod|<=1 (product of
// cosines) => f,i <= sigma(1)=0.7311, |u| <= tanh(1)=0.7616 => fixed point
// bound |cc| <= 0.557/(1-0.7311) = 2.07. On these ranges Pade[5/4] tanh
// (continued-fraction x(945+105x^2+x^4)/(945+420x^2+15x^4)) is accurate to
// <1.5e-4, so both exp+rcp pairs become fma+rcp. Chain/step ~650 -> ~300 cyc.

#define T_STEPS 128
#define B_SZ    256
#define D_IN    64
#define H_SZ    10
#define COMB    74   // D_IN + H_SZ

// ---------------- DPP helpers (16-lane rows match our gate segments) --------
template<int CTRL>
__device__ __forceinline__ float dpp_mov(float old_, float src) {
    return __int_as_float(__builtin_amdgcn_update_dpp(
        __float_as_int(old_), __float_as_int(src), CTRL, 0xF, 0xF, false));
}
#define DPP_ROW_SHR(n) (0x110 + (n))
#define DPP_ROW_ROR(n) (0x120 + (n))

__device__ __forceinline__ float rdlane(float v, int lane) {
    return __int_as_float(__builtin_amdgcn_readlane(__float_as_int(v), lane));
}
__device__ __forceinline__ float bperm(int lane, float v) {
    return __int_as_float(__builtin_amdgcn_ds_bpermute(4 * lane, __float_as_int(v)));
}
__device__ __forceinline__ float frcp(float x) { return __builtin_amdgcn_rcpf(x); }

// Pade [5/4] tanh: exact-to-1e-4 on |x| <= ~2.5 (all our inputs are bounded)
__device__ __forceinline__ float tanh_pade(float x) {
    float x2  = x * x;
    float num = x * fmaf(x2, (x2 + 105.f), 945.f);
    float den = fmaf(x2, fmaf(x2, 15.f, 420.f), 945.f);
    return num * frcp(den);
}

// ---------------- Kernel 1: Zx[b][gw][t] = b + x[t,b,:] . W[gw,0:64] --------
__global__ __launch_bounds__(64) void qlstm_pre(
    const float* __restrict__ x,
    const float* __restrict__ Wf, const float* __restrict__ bf,
    const float* __restrict__ Wi, const float* __restrict__ bi,
    const float* __restrict__ Wu, const float* __restrict__ bu,
    const float* __restrict__ Wo, const float* __restrict__ bo,
    float* __restrict__ Zx)
{
    __shared__ float Wl[40 * 64];
    __shared__ float bl[40];

    const int tid = threadIdx.x;
    const long r0 = (long)blockIdx.x * 128 + tid;   // rows r0 and r0+64
    const long r1 = r0 + 64;

    const float* Ws[4] = {Wf, Wi, Wu, Wo};
    const float* bs[4] = {bf, bi, bu, bo};
#pragma unroll
    for (int k = 0; k < 40; k++) {                  // coalesced 64-float rows
        int gg = k / 10, w = k - gg * 10;
        Wl[k * 64 + tid] = Ws[gg][w * COMB + tid];
    }
    if (tid < 40) { int gg = tid / 10, w = tid - gg * 10; bl[tid] = bs[gg][w]; }
    __syncthreads();

    float xr0[64], xr1[64];
    const float4* xin0 = (const float4*)(x + r0 * D_IN);
    const float4* xin1 = (const float4*)(x + r1 * D_IN);
#pragma unroll
    for (int k = 0; k < 16; k++) {
        float4 v0 = xin0[k];
        xr0[4*k+0] = v0.x; xr0[4*k+1] = v0.y; xr0[4*k+2] = v0.z; xr0[4*k+3] = v0.w;
        float4 v1 = xin1[k];
        xr1[4*k+0] = v1.x; xr1[4*k+1] = v1.y; xr1[4*k+2] = v1.z; xr1[4*k+3] = v1.w;
    }

    const int t0 = (int)(r0 >> 8), b0 = (int)(r0 & 255);
    const int t1 = (int)(r1 >> 8), b1 = (int)(r1 & 255);
    float* z0 = Zx + (size_t)b0 * 40 * T_STEPS + t0;
    float* z1 = Zx + (size_t)b1 * 40 * T_STEPS + t1;

#pragma unroll
    for (int gw = 0; gw < 40; gw++) {
        float a0 = bl[gw], a1 = bl[gw];
        const float4* wr4 = (const float4*)(Wl + gw * 64);
#pragma unroll
        for (int d4 = 0; d4 < 16; d4++) {           // uniform ds_read_b128
            float4 wv = wr4[d4];
            a0 = fmaf(xr0[4*d4+0], wv.x, a0);
            a0 = fmaf(xr0[4*d4+1], wv.y, a0);
            a0 = fmaf(xr0[4*d4+2], wv.z, a0);
            a0 = fmaf(xr0[4*d4+3], wv.w, a0);
            a1 = fmaf(xr1[4*d4+0], wv.x, a1);
            a1 = fmaf(xr1[4*d4+1], wv.y, a1);
            a1 = fmaf(xr1[4*d4+2], wv.z, a1);
            a1 = fmaf(xr1[4*d4+3], wv.w, a1);
        }
        z0[(size_t)gw * T_STEPS] = a0;              // [b][gw][t] scatter
        z1[(size_t)gw * T_STEPS] = a1;
    }
}

// ---------------- Kernel 2: sequential recurrence, one wave per batch -------
__global__ __launch_bounds__(64) void qlstm_rec(
    const float* __restrict__ Zx,
    const float* __restrict__ Wf, const float* __restrict__ Wi,
    const float* __restrict__ Wu, const float* __restrict__ Wo,
    const float* __restrict__ pf, const float* __restrict__ pi,
    const float* __restrict__ pu, const float* __restrict__ po,
    const float* __restrict__ ln_g, const float* __restrict__ ln_b,
    float* __restrict__ ys, float* __restrict__ outH, float* __restrict__ outC)
{
    const int b    = blockIdx.x;
    const int lane = threadIdx.x;
    const int g    = lane >> 4;        // gate 0..3 = f,i,u,o
    const int w    = lane & 15;        // wire 0..15 (10 active)
    const bool act = (w < H_SZ);

    const float* Ws[4] = {Wf, Wi, Wu, Wo};
    const float* ps[4] = {pf, pi, pu, po};

    // LN folded into the recurrence:
    //   sum_j wh[j]*hnew[j] = rstd*(sum_j wh'[j]*hraw[j] - mu*S) + A
    float whp[H_SZ];
    float S = 0.f, A = 0.f;
#pragma unroll
    for (int j = 0; j < H_SZ; j++) {
        float whj = act ? Ws[g][w * COMB + D_IN + j] : 0.f;
        whp[j] = whj * ln_g[j];
        S += whp[j];
        A  = fmaf(whj, ln_b[j], A);
    }
    const float p0  = act ? ps[g][w * 3 + 0] : 0.f;
    const float cp1 = act ? __cosf(ps[g][w * 3 + 1]) : 1.f;
    const float lng = act ? ln_g[w] : 0.f;
    const float lnb = act ? ln_b[w] : 0.f;
    // gate u (g==2): tanh(q); others: sigmoid(q) = 0.5 + 0.5*tanh(q/2)
    const float s0 = (g == 2) ? 0.f : 0.5f;
    const float s1 = (g == 2) ? 1.f : 0.5f;
    const float sc = (g == 2) ? 1.f : 0.5f;

    float hn = 0.f;      // normalized h[w] (valid in lanes 0..9)
    float cc = 0.f;      // c[w]
    float hterm = 0.f;   // sum_j wh[j]*h[j] contribution to this lane's z

    // Zx[b][gw][t]: per-lane contiguous t-stream; 4 steps per dwordx4,
    // 2-buffer rotation -> loads consumed 8 steps after issue.
    const int gwl = g * 10 + (act ? w : 9);
    const float* zb = Zx + ((size_t)b * 40 + gwl) * T_STEPS;
    float4 zb0 = *(const float4*)(zb);
    float4 zb1 = *(const float4*)(zb + 4);

    float* ysb = ys + (size_t)b * H_SZ + lane;   // stride 2560 floats per t

    for (int gq = 0; gq < T_STEPS / 4; gq++) {
        float4 zc = zb0;
        zb0 = zb1;
        const int nl = (gq + 2 < T_STEPS / 4) ? gq + 2 : T_STEPS / 4 - 1;
        zb1 = *(const float4*)(zb + (size_t)nl * 4);

        float zs[4] = {zc.x, zc.y, zc.z, zc.w};
#pragma unroll
        for (int j = 0; j < 4; j++) {
            const int t = gq * 4 + j;
            float z = zs[j] + hterm;

            // per-wire <Z> factor, segmented inclusive cumprod (DPP row ops)
            float prod = cp1 * __cosf(p0 + z);
            prod *= dpp_mov<DPP_ROW_SHR(1)>(1.f, prod);
            prod *= dpp_mov<DPP_ROW_SHR(2)>(1.f, prod);
            prod *= dpp_mov<DPP_ROW_SHR(4)>(1.f, prod);
            prod *= dpp_mov<DPP_ROW_SHR(8)>(1.f, prod);

            // branchless activation via Pade tanh (|prod| <= 1)
            float av = fmaf(s1, tanh_pade(sc * prod), s0);

            // gather the 4 gates' activations for this lane's w
            float fw = bperm(w,      av);
            float iw = bperm(w + 16, av);
            float uw = bperm(w + 32, av);
            float ow = bperm(w + 48, av);

            cc = fmaf(fw, cc, iw * uw);
            float tc   = tanh_pade(cc);             // |cc| <= 2.07 (bounded)
            float hraw = fmaf(ow, tc, hn);          // residual skip

            // LN stats: rotate-allreduce over the 16-lane segment
            float v1 = act ? hraw : 0.f;
            float v2 = v1 * v1;
            v1 += dpp_mov<DPP_ROW_ROR(8)>(0.f, v1);
            v2 += dpp_mov<DPP_ROW_ROR(8)>(0.f, v2);
            v1 += dpp_mov<DPP_ROW_ROR(4)>(0.f, v1);
            v2 += dpp_mov<DPP_ROW_ROR(4)>(0.f, v2);
            v1 += dpp_mov<DPP_ROW_ROR(2)>(0.f, v1);
            v2 += dpp_mov<DPP_ROW_ROR(2)>(0.f, v2);
            v1 += dpp_mov<DPP_ROW_ROR(1)>(0.f, v1);
            v2 += dpp_mov<DPP_ROW_ROR(1)>(0.f, v2);

            // D = sum_j wh'[j]*hraw[j] via readlane (overlaps the DPP reduce)
            float d0 = whp[0] * rdlane(hraw, 0);
            float d1 = whp[1] * rdlane(hraw, 1);
            d0 = fmaf(whp[2], rdlane(hraw, 2), d0);
            d1 = fmaf(whp[3], rdlane(hraw, 3), d1);
            d0 = fmaf(whp[4], rdlane(hraw, 4), d0);
            d1 = fmaf(whp[5], rdlane(hraw, 5), d1);
            d0 = fmaf(whp[6], rdlane(hraw, 6), d0);
            d1 = fmaf(whp[7], rdlane(hraw, 7), d1);
            d0 = fmaf(whp[8], rdlane(hraw, 8), d0);
            d1 = fmaf(whp[9], rdlane(hraw, 9), d1);
            float D = d0 + d1;

            float mu   = v1 * 0.1f;
            float varr = fmaxf(fmaf(v2, 0.1f, -mu * mu), 0.f);
            float rstd = __builtin_amdgcn_rsqf(varr + 1e-5f);

            hn    = fmaf((hraw - mu) * rstd, lng, lnb);
            hterm = fmaf(rstd, fmaf(-mu, S, D), A);

            if (lane < H_SZ)
                ysb[(size_t)t * B_SZ * H_SZ] = hn;
        }
    }

    if (lane < H_SZ) {
        outH[b * H_SZ + lane] = hn;
        outC[b * H_SZ + lane] = cc;
    }
}

extern "C" void kernel_launch(void* const* d_in, const int* in_sizes, int n_in,
                              void* d_out, int out_size, void* d_ws, size_t ws_size,
                              hipStream_t stream)
{
    const float* x    = (const float*)d_in[0];
    const float* Wf   = (const float*)d_in[1];
    const float* bf   = (const float*)d_in[2];
    const float* pf   = (const float*)d_in[3];
    const float* Wi   = (const float*)d_in[4];
    const float* bi   = (const float*)d_in[5];
    const float* pi   = (const float*)d_in[6];
    const float* Wu   = (const float*)d_in[7];
    const float* bu   = (const float*)d_in[8];
    const float* pu   = (const float*)d_in[9];
    const float* Wo   = (const float*)d_in[10];
    const float* bo   = (const float*)d_in[11];
    const float* po   = (const float*)d_in[12];
    const float* ln_g = (const float*)d_in[13];
    const float* ln_b = (const float*)d_in[14];

    float* Zx = (float*)d_ws;                 // B*40*T floats = 5.24 MB

    float* ys   = (float*)d_out;              // (T,B,H)
    float* outH = ys + (size_t)T_STEPS * B_SZ * H_SZ;
    float* outC = outH + (size_t)B_SZ * H_SZ;

    qlstm_pre<<<(T_STEPS * B_SZ) / 128, 64, 0, stream>>>(
        x, Wf, bf, Wi, bi, Wu, bu, Wo, bo, Zx);

    qlstm_rec<<<B_SZ, 64, 0, stream>>>(
        Zx, Wf, Wi, Wu, Wo, pf, pi, pu, po, ln_g, ln_b, ys, outH, outC);
}